// Round 5
// baseline (745.005 us; speedup 1.0000x reference)
//
#include <hip/hip_runtime.h>
#include <hip/hip_bf16.h>

// ---------------------------------------------------------------------------
// 2-layer GCN on MI355X.
//   relu(agg(X@W)+b) == relu(agg(X)@W + b)   (agg is linear)
// CSR build without random scatter (bucket partition), then per layer ONE
// fused kernel: block = 64-node tile; phase 1 waves gather/aggregate rows
// into LDS; phase 2 register-tiled 64x64 GEMM + bias + relu from LDS.
// Requires n < 2^17 (src packed in 17 bits; n = 100000 here).
// ---------------------------------------------------------------------------

#define NB_SHIFT 7
#define NB_MASK  ((1 << NB_SHIFT) - 1)
#define EPB      8192              // edges per block in bhist/part
#define XS_LD    68                // LDS row stride (floats): 16B-aligned, 2-way max

__global__ __launch_bounds__(256) void k_bhist(const int* __restrict__ dst,
                                               int* __restrict__ bcnt,
                                               int ne, int nb) {
    __shared__ int lh[1024];
    for (int t = threadIdx.x; t < nb; t += 256) lh[t] = 0;
    __syncthreads();
    const int beg = blockIdx.x * EPB;
    const int end = min(beg + EPB, ne);
    for (int e = beg + threadIdx.x; e < end; e += 256)
        atomicAdd(&lh[dst[e] >> NB_SHIFT], 1);
    __syncthreads();
    for (int t = threadIdx.x; t < nb; t += 256)
        if (lh[t]) atomicAdd(&bcnt[t], lh[t]);
}

__global__ __launch_bounds__(64) void k_bscan(const int* __restrict__ bcnt,
                                              int* __restrict__ bbase,
                                              int* __restrict__ bcur, int nb,
                                              int* __restrict__ offsets,
                                              int n, int ne) {
    const int lane = threadIdx.x;
    int carry = 0;
    for (int base = 0; base < nb; base += 64) {
        int i = base + lane;
        int v = (i < nb) ? bcnt[i] : 0;
        int x = v;
        #pragma unroll
        for (int off = 1; off < 64; off <<= 1) {
            int t = __shfl_up(x, off);
            if (lane >= off) x += t;
        }
        if (i < nb) { int excl = carry + x - v; bbase[i] = excl; bcur[i] = excl; }
        carry += __shfl(x, 63);
    }
    if (lane == 0) { bbase[nb] = carry; offsets[n] = ne; }
}

__global__ __launch_bounds__(256) void k_part(const int* __restrict__ src,
                                              const int* __restrict__ dst,
                                              int* __restrict__ bcur,
                                              unsigned* __restrict__ tpack,
                                              int ne, int nb) {
    __shared__ int lh[1024];
    __shared__ int lbase[1024];
    __shared__ int lrk[1024];
    for (int t = threadIdx.x; t < nb; t += 256) { lh[t] = 0; lrk[t] = 0; }
    __syncthreads();
    const int beg = blockIdx.x * EPB;
    const int end = min(beg + EPB, ne);
    for (int e = beg + threadIdx.x; e < end; e += 256)
        atomicAdd(&lh[dst[e] >> NB_SHIFT], 1);
    __syncthreads();
    for (int t = threadIdx.x; t < nb; t += 256)
        lbase[t] = lh[t] ? atomicAdd(&bcur[t], lh[t]) : 0;
    __syncthreads();
    for (int e = beg + threadIdx.x; e < end; e += 256) {
        int d = dst[e], s = src[e];
        int b = d >> NB_SHIFT;
        int r = atomicAdd(&lrk[b], 1);
        tpack[lbase[b] + r] = (unsigned)s | ((unsigned)(d & NB_MASK) << 17);
    }
}

__global__ __launch_bounds__(256) void k_bin(const unsigned* __restrict__ tpack,
                                             const int* __restrict__ bbase,
                                             int* __restrict__ csrc,
                                             int* __restrict__ offsets,
                                             float* __restrict__ dinv, int n) {
    __shared__ int hist[128], loff[128], cur[128];
    const int b = blockIdx.x;
    const int ebeg = bbase[b], eend = bbase[b + 1];
    const int dbase = b << NB_SHIFT;
    if (threadIdx.x < 128) { hist[threadIdx.x] = 0; cur[threadIdx.x] = 0; }
    __syncthreads();
    for (int e = ebeg + threadIdx.x; e < eend; e += 256)
        atomicAdd(&hist[tpack[e] >> 17], 1);
    __syncthreads();
    if (threadIdx.x < 64) {   // wave 0: exclusive scan of hist[0..127]
        const int lane = threadIdx.x;
        int v0 = hist[lane], v1 = hist[64 + lane];
        int x0 = v0, x1 = v1;
        #pragma unroll
        for (int off = 1; off < 64; off <<= 1) {
            int t0 = __shfl_up(x0, off); if (lane >= off) x0 += t0;
            int t1 = __shfl_up(x1, off); if (lane >= off) x1 += t1;
        }
        int sum0 = __shfl(x0, 63);
        loff[lane]      = x0 - v0;
        loff[64 + lane] = sum0 + x1 - v1;
    }
    __syncthreads();
    if (threadIdx.x < 128) {
        int d = dbase + threadIdx.x;
        if (d < n) {
            offsets[d] = ebeg + loff[threadIdx.x];
            dinv[d]    = rsqrtf((float)(hist[threadIdx.x] + 1));  // +1 self loop
        }
    }
    __syncthreads();
    for (int e = ebeg + threadIdx.x; e < eend; e += 256) {
        unsigned p = tpack[e];
        int dl = (int)(p >> 17);
        int s  = (int)(p & 0x1FFFFu);
        int r  = atomicAdd(&cur[dl], 1);
        csrc[ebeg + loff[dl] + r] = s;
    }
}

// ---------------------------------------------------------------------------
// Fused: H[tile] = relu( agg(X)[tile] @ W + bias )
// Phase 1: wave w aggregates nodes tbase+w*16 .. +15 into Xs (LDS).
//          quarter-wave per edge (sub = lane>>4), float4 feature groups,
//          2 edges in flight per lane (8 edges/iter).
// Phase 2: 4x4 register micro-tile GEMM from Xs(LDS) x Wl(LDS), bias+relu.
// ---------------------------------------------------------------------------
#define GEMM_ACC(ai, xi)                                                  \
    ai.x = fmaf(xi.x, w0.x, ai.x); ai.y = fmaf(xi.x, w0.y, ai.y);         \
    ai.z = fmaf(xi.x, w0.z, ai.z); ai.w = fmaf(xi.x, w0.w, ai.w);         \
    ai.x = fmaf(xi.y, w1.x, ai.x); ai.y = fmaf(xi.y, w1.y, ai.y);         \
    ai.z = fmaf(xi.y, w1.z, ai.z); ai.w = fmaf(xi.y, w1.w, ai.w);         \
    ai.x = fmaf(xi.z, w2.x, ai.x); ai.y = fmaf(xi.z, w2.y, ai.y);         \
    ai.z = fmaf(xi.z, w2.z, ai.z); ai.w = fmaf(xi.z, w2.w, ai.w);         \
    ai.x = fmaf(xi.w, w3.x, ai.x); ai.y = fmaf(xi.w, w3.y, ai.y);         \
    ai.z = fmaf(xi.w, w3.z, ai.z); ai.w = fmaf(xi.w, w3.w, ai.w);

#define GEMM_STORE(ai, idx)                                               \
    if (r0 + idx < n) {                                                   \
        float4 r;                                                         \
        r.x = fmaxf(ai.x + bv.x, 0.f); r.y = fmaxf(ai.y + bv.y, 0.f);     \
        r.z = fmaxf(ai.z + bv.z, 0.f); r.w = fmaxf(ai.w + bv.w, 0.f);     \
        *(float4*)(H + (size_t)(r0 + idx) * 64 + c0) = r;                 \
    }

__global__ __launch_bounds__(256) void k_fused(const float* __restrict__ X,
                                               const float* __restrict__ W,
                                               const float* __restrict__ bias,
                                               const int* __restrict__ offsets,
                                               const int* __restrict__ csrc,
                                               const float* __restrict__ dinv,
                                               float* __restrict__ H, int n) {
    __shared__ float Wl[64 * 64];
    __shared__ float Xs[64][XS_LD];
    {   // vectorized W stage
        const float4* Wv = (const float4*)W;
        float4* Wlv = (float4*)Wl;
        for (int t = threadIdx.x; t < 1024; t += 256) Wlv[t] = Wv[t];
    }
    const int lane = threadIdx.x & 63;
    const int wid  = threadIdx.x >> 6;
    const int sub  = lane >> 4;          // 0..3 edge sub-slot
    const int f0   = (lane & 15) * 4;    // feature offset
    const int tbase = blockIdx.x * 64;

    // ---- phase 1: aggregate 16 nodes per wave into LDS ----
    for (int j = 0; j < 16; ++j) {
        const int r = wid * 16 + j;      // local row 0..63
        const int i = tbase + r;
        float4 acc = {0.f, 0.f, 0.f, 0.f};
        if (i < n) {
            const int beg = offsets[i], end = offsets[i + 1];
            const float di = dinv[i];
            for (int base = beg; base < end; base += 8) {
                const int e0 = base + sub;
                const int e1 = e0 + 4;
                const bool v0 = e0 < end, v1 = e1 < end;
                int s0 = 0, s1 = 0;
                if (v0) s0 = csrc[e0];
                if (v1) s1 = csrc[e1];
                const float4 h0 = *(const float4*)(X + (size_t)s0 * 64 + f0);
                const float4 h1 = *(const float4*)(X + (size_t)s1 * 64 + f0);
                const float w0 = v0 ? dinv[s0] * di : 0.f;
                const float w1 = v1 ? dinv[s1] * di : 0.f;
                acc.x = fmaf(w1, h1.x, fmaf(w0, h0.x, acc.x));
                acc.y = fmaf(w1, h1.y, fmaf(w0, h0.y, acc.y));
                acc.z = fmaf(w1, h1.z, fmaf(w0, h0.z, acc.z));
                acc.w = fmaf(w1, h1.w, fmaf(w0, h0.w, acc.w));
            }
            // reduce 4 sub-slot partials
            acc.x += __shfl_xor(acc.x, 16); acc.x += __shfl_xor(acc.x, 32);
            acc.y += __shfl_xor(acc.y, 16); acc.y += __shfl_xor(acc.y, 32);
            acc.z += __shfl_xor(acc.z, 16); acc.z += __shfl_xor(acc.z, 32);
            acc.w += __shfl_xor(acc.w, 16); acc.w += __shfl_xor(acc.w, 32);
            const float ws = di * di;     // self loop
            const float4 xs = *(const float4*)(X + (size_t)i * 64 + f0);
            acc.x = fmaf(ws, xs.x, acc.x);
            acc.y = fmaf(ws, xs.y, acc.y);
            acc.z = fmaf(ws, xs.z, acc.z);
            acc.w = fmaf(ws, xs.w, acc.w);
        }
        if (lane < 16) *(float4*)(&Xs[r][f0]) = acc;   // zeros when i >= n
    }
    __syncthreads();

    // ---- phase 2: 64x64 GEMM from LDS ----
    const int cg = threadIdx.x & 15;
    const int rg = threadIdx.x >> 4;
    const int c0 = cg * 4;
    const int r0 = tbase + rg * 4;
    const float4 bv = *(const float4*)(bias + c0);
    float4 a0 = {0,0,0,0}, a1 = {0,0,0,0}, a2 = {0,0,0,0}, a3 = {0,0,0,0};
    #pragma unroll
    for (int k = 0; k < 64; k += 4) {
        const float4 x0 = *(const float4*)(&Xs[rg * 4 + 0][k]);
        const float4 x1 = *(const float4*)(&Xs[rg * 4 + 1][k]);
        const float4 x2 = *(const float4*)(&Xs[rg * 4 + 2][k]);
        const float4 x3 = *(const float4*)(&Xs[rg * 4 + 3][k]);
        const float4 w0 = *(const float4*)(&Wl[(k + 0) * 64 + c0]);
        const float4 w1 = *(const float4*)(&Wl[(k + 1) * 64 + c0]);
        const float4 w2 = *(const float4*)(&Wl[(k + 2) * 64 + c0]);
        const float4 w3 = *(const float4*)(&Wl[(k + 3) * 64 + c0]);
        GEMM_ACC(a0, x0)
        GEMM_ACC(a1, x1)
        GEMM_ACC(a2, x2)
        GEMM_ACC(a3, x3)
    }
    GEMM_STORE(a0, 0)
    GEMM_STORE(a1, 1)
    GEMM_STORE(a2, 2)
    GEMM_STORE(a3, 3)
}

extern "C" void kernel_launch(void* const* d_in, const int* in_sizes, int n_in,
                              void* d_out, int out_size, void* d_ws, size_t ws_size,
                              hipStream_t stream) {
    const float* emb = (const float*)d_in[0];
    const float* W1  = (const float*)d_in[1];
    const float* b1  = (const float*)d_in[2];
    const float* W2  = (const float*)d_in[3];
    const float* b2  = (const float*)d_in[4];
    const int*   ei  = (const int*)d_in[5];

    const int n  = in_sizes[0] / 64;   // 100000 nodes (< 2^17, fits pack)
    const int ne = in_sizes[5] / 2;    // 1600000 edges
    const int* src = ei;
    const int* dst = ei + ne;
    const int nb = (n + NB_MASK) >> NB_SHIFT;   // 782 buckets

    // ---- workspace layout (~39 MB) ----
    char* ws = (char*)d_ws;
    size_t off = 0;
    auto alloc = [&](size_t bytes) { void* p = ws + off; off = (off + bytes + 63) & ~size_t(63); return p; };
    int*      bcnt    = (int*)     alloc((size_t)nb * 4);
    int*      bbase   = (int*)     alloc((size_t)(nb + 1) * 4);
    int*      bcur    = (int*)     alloc((size_t)nb * 4);
    unsigned* tpack   = (unsigned*)alloc((size_t)ne * 4);
    int*      csrc    = (int*)     alloc((size_t)ne * 4);
    int*      offsets = (int*)     alloc((size_t)(n + 1) * 4);
    float*    dinv    = (float*)   alloc((size_t)n * 4);
    float*    Y       = (float*)   alloc((size_t)n * 64 * 4);   // layer-1 output
    (void)ws_size;

    float* out = (float*)d_out;

    hipMemsetAsync(bcnt, 0, (size_t)nb * 4, stream);

    const int pb = (ne + EPB - 1) / EPB;   // partition blocks
    const int fb = (n + 63) / 64;          // fused tiles

    k_bhist<<<pb, 256, 0, stream>>>(dst, bcnt, ne, nb);
    k_bscan<<<1, 64, 0, stream>>>(bcnt, bbase, bcur, nb, offsets, n, ne);
    k_part <<<pb, 256, 0, stream>>>(src, dst, bcur, tpack, ne, nb);
    k_bin  <<<nb, 256, 0, stream>>>(tpack, bbase, csrc, offsets, dinv, n);

    // layer 1: gather emb, write Y; layer 2: gather Y, write out (never same buf)
    k_fused<<<fb, 256, 0, stream>>>(emb, W1, b1, offsets, csrc, dinv, Y, n);
    k_fused<<<fb, 256, 0, stream>>>(Y,   W2, b2, offsets, csrc, dinv, out, n);
}

// Round 6
// 323.870 us; speedup vs baseline: 2.3003x; 2.3003x over previous
//
#include <hip/hip_runtime.h>
#include <hip/hip_bf16.h>

// ---------------------------------------------------------------------------
// 2-layer GCN on MI355X.
//   relu(agg(X@W)+b) == relu(agg(X)@W + b)   (agg is linear)
// CSR build without random scatter (bucket partition):
//   k_bhist / k_bscan / k_part / k_bin  (as round 4)
// Aggregation: k_agg, wave per node, quarter-wave per edge, 16 edges/iter
//   in flight (4 independent gathers per lane) -> latency hiding via MLP.
// GEMM: separate k_gemm64 (bias+relu fused), high occupancy preserved.
// Requires n < 2^17 (src packed in 17 bits; n = 100000 here).
// ---------------------------------------------------------------------------

#define NB_SHIFT 7
#define NB_MASK  ((1 << NB_SHIFT) - 1)
#define EPB      8192              // edges per block in bhist/part

__global__ __launch_bounds__(256) void k_bhist(const int* __restrict__ dst,
                                               int* __restrict__ bcnt,
                                               int ne, int nb) {
    __shared__ int lh[1024];
    for (int t = threadIdx.x; t < nb; t += 256) lh[t] = 0;
    __syncthreads();
    const int beg = blockIdx.x * EPB;
    const int end = min(beg + EPB, ne);
    for (int e = beg + threadIdx.x; e < end; e += 256)
        atomicAdd(&lh[dst[e] >> NB_SHIFT], 1);
    __syncthreads();
    for (int t = threadIdx.x; t < nb; t += 256)
        if (lh[t]) atomicAdd(&bcnt[t], lh[t]);
}

__global__ __launch_bounds__(64) void k_bscan(const int* __restrict__ bcnt,
                                              int* __restrict__ bbase,
                                              int* __restrict__ bcur, int nb,
                                              int* __restrict__ offsets,
                                              int n, int ne) {
    const int lane = threadIdx.x;
    int carry = 0;
    for (int base = 0; base < nb; base += 64) {
        int i = base + lane;
        int v = (i < nb) ? bcnt[i] : 0;
        int x = v;
        #pragma unroll
        for (int off = 1; off < 64; off <<= 1) {
            int t = __shfl_up(x, off);
            if (lane >= off) x += t;
        }
        if (i < nb) { int excl = carry + x - v; bbase[i] = excl; bcur[i] = excl; }
        carry += __shfl(x, 63);
    }
    if (lane == 0) { bbase[nb] = carry; offsets[n] = ne; }
}

__global__ __launch_bounds__(256) void k_part(const int* __restrict__ src,
                                              const int* __restrict__ dst,
                                              int* __restrict__ bcur,
                                              unsigned* __restrict__ tpack,
                                              int ne, int nb) {
    __shared__ int lh[1024];
    __shared__ int lbase[1024];
    __shared__ int lrk[1024];
    for (int t = threadIdx.x; t < nb; t += 256) { lh[t] = 0; lrk[t] = 0; }
    __syncthreads();
    const int beg = blockIdx.x * EPB;
    const int end = min(beg + EPB, ne);
    for (int e = beg + threadIdx.x; e < end; e += 256)
        atomicAdd(&lh[dst[e] >> NB_SHIFT], 1);
    __syncthreads();
    for (int t = threadIdx.x; t < nb; t += 256)
        lbase[t] = lh[t] ? atomicAdd(&bcur[t], lh[t]) : 0;
    __syncthreads();
    for (int e = beg + threadIdx.x; e < end; e += 256) {
        int d = dst[e], s = src[e];
        int b = d >> NB_SHIFT;
        int r = atomicAdd(&lrk[b], 1);
        tpack[lbase[b] + r] = (unsigned)s | ((unsigned)(d & NB_MASK) << 17);
    }
}

__global__ __launch_bounds__(256) void k_bin(const unsigned* __restrict__ tpack,
                                             const int* __restrict__ bbase,
                                             int* __restrict__ csrc,
                                             int* __restrict__ offsets,
                                             float* __restrict__ dinv, int n) {
    __shared__ int hist[128], loff[128], cur[128];
    const int b = blockIdx.x;
    const int ebeg = bbase[b], eend = bbase[b + 1];
    const int dbase = b << NB_SHIFT;
    if (threadIdx.x < 128) { hist[threadIdx.x] = 0; cur[threadIdx.x] = 0; }
    __syncthreads();
    for (int e = ebeg + threadIdx.x; e < eend; e += 256)
        atomicAdd(&hist[tpack[e] >> 17], 1);
    __syncthreads();
    if (threadIdx.x < 64) {   // wave 0: exclusive scan of hist[0..127]
        const int lane = threadIdx.x;
        int v0 = hist[lane], v1 = hist[64 + lane];
        int x0 = v0, x1 = v1;
        #pragma unroll
        for (int off = 1; off < 64; off <<= 1) {
            int t0 = __shfl_up(x0, off); if (lane >= off) x0 += t0;
            int t1 = __shfl_up(x1, off); if (lane >= off) x1 += t1;
        }
        int sum0 = __shfl(x0, 63);
        loff[lane]      = x0 - v0;
        loff[64 + lane] = sum0 + x1 - v1;
    }
    __syncthreads();
    if (threadIdx.x < 128) {
        int d = dbase + threadIdx.x;
        if (d < n) {
            offsets[d] = ebeg + loff[threadIdx.x];
            dinv[d]    = rsqrtf((float)(hist[threadIdx.x] + 1));  // +1 self loop
        }
    }
    __syncthreads();
    for (int e = ebeg + threadIdx.x; e < eend; e += 256) {
        unsigned p = tpack[e];
        int dl = (int)(p >> 17);
        int s  = (int)(p & 0x1FFFFu);
        int r  = atomicAdd(&cur[dl], 1);
        csrc[ebeg + loff[dl] + r] = s;
    }
}

// Y[i,:] = dinv[i]^2 * X[i,:] + sum_e dinv[s]*dinv[i] * X[s,:]
// wave per node; quarter-wave per edge slot; 16 edges in flight per iter
// (4 per lane). Invalid slots clamp to src row 0 with w=0 (L1-hot, cheap).
__global__ __launch_bounds__(256) void k_agg(const float* __restrict__ X,
                                             const int* __restrict__ offsets,
                                             const int* __restrict__ csrc,
                                             const float* __restrict__ dinv,
                                             float* __restrict__ Y, int n) {
    const int lane = threadIdx.x & 63;
    const int sub  = lane >> 4;          // 0..3 edge sub-slot
    const int f0   = (lane & 15) * 4;    // feature offset
    const int i    = (blockIdx.x * 256 + threadIdx.x) >> 6;
    if (i >= n) return;
    const int beg = offsets[i], end = offsets[i + 1];
    const float di = dinv[i];
    float4 acc = {0.f, 0.f, 0.f, 0.f};
    for (int base = beg; base < end; base += 16) {
        const int e0 = base + sub;
        const int e1 = e0 + 4;
        const int e2 = e0 + 8;
        const int e3 = e0 + 12;
        int s0 = 0, s1 = 0, s2 = 0, s3 = 0;
        if (e0 < end) s0 = csrc[e0];
        if (e1 < end) s1 = csrc[e1];
        if (e2 < end) s2 = csrc[e2];
        if (e3 < end) s3 = csrc[e3];
        // 4 independent row gathers in flight
        const float4 h0 = *(const float4*)(X + (size_t)s0 * 64 + f0);
        const float4 h1 = *(const float4*)(X + (size_t)s1 * 64 + f0);
        const float4 h2 = *(const float4*)(X + (size_t)s2 * 64 + f0);
        const float4 h3 = *(const float4*)(X + (size_t)s3 * 64 + f0);
        const float w0 = (e0 < end) ? dinv[s0] * di : 0.f;
        const float w1 = (e1 < end) ? dinv[s1] * di : 0.f;
        const float w2 = (e2 < end) ? dinv[s2] * di : 0.f;
        const float w3 = (e3 < end) ? dinv[s3] * di : 0.f;
        acc.x = fmaf(w0, h0.x, acc.x); acc.y = fmaf(w0, h0.y, acc.y);
        acc.z = fmaf(w0, h0.z, acc.z); acc.w = fmaf(w0, h0.w, acc.w);
        acc.x = fmaf(w1, h1.x, acc.x); acc.y = fmaf(w1, h1.y, acc.y);
        acc.z = fmaf(w1, h1.z, acc.z); acc.w = fmaf(w1, h1.w, acc.w);
        acc.x = fmaf(w2, h2.x, acc.x); acc.y = fmaf(w2, h2.y, acc.y);
        acc.z = fmaf(w2, h2.z, acc.z); acc.w = fmaf(w2, h2.w, acc.w);
        acc.x = fmaf(w3, h3.x, acc.x); acc.y = fmaf(w3, h3.y, acc.y);
        acc.z = fmaf(w3, h3.z, acc.z); acc.w = fmaf(w3, h3.w, acc.w);
    }
    // reduce the 4 sub-slot partials (lanes l, l^16, l^32, l^48)
    acc.x += __shfl_xor(acc.x, 16); acc.x += __shfl_xor(acc.x, 32);
    acc.y += __shfl_xor(acc.y, 16); acc.y += __shfl_xor(acc.y, 32);
    acc.z += __shfl_xor(acc.z, 16); acc.z += __shfl_xor(acc.z, 32);
    acc.w += __shfl_xor(acc.w, 16); acc.w += __shfl_xor(acc.w, 32);
    const float ws = di * di;
    const float4 xs = *(const float4*)(X + (size_t)i * 64 + f0);
    acc.x = fmaf(ws, xs.x, acc.x);
    acc.y = fmaf(ws, xs.y, acc.y);
    acc.z = fmaf(ws, xs.z, acc.z);
    acc.w = fmaf(ws, xs.w, acc.w);
    if (lane < 16) *(float4*)(Y + (size_t)i * 64 + f0) = acc;
}

// H = relu(X @ W + bias); 4x4 micro-tile per thread, 64x64 tile per block.
#define GEMM_ACC(ai, xi)                                                  \
    ai.x = fmaf(xi.x, w0.x, ai.x); ai.y = fmaf(xi.x, w0.y, ai.y);         \
    ai.z = fmaf(xi.x, w0.z, ai.z); ai.w = fmaf(xi.x, w0.w, ai.w);         \
    ai.x = fmaf(xi.y, w1.x, ai.x); ai.y = fmaf(xi.y, w1.y, ai.y);         \
    ai.z = fmaf(xi.y, w1.z, ai.z); ai.w = fmaf(xi.y, w1.w, ai.w);         \
    ai.x = fmaf(xi.z, w2.x, ai.x); ai.y = fmaf(xi.z, w2.y, ai.y);         \
    ai.z = fmaf(xi.z, w2.z, ai.z); ai.w = fmaf(xi.z, w2.w, ai.w);         \
    ai.x = fmaf(xi.w, w3.x, ai.x); ai.y = fmaf(xi.w, w3.y, ai.y);         \
    ai.z = fmaf(xi.w, w3.z, ai.z); ai.w = fmaf(xi.w, w3.w, ai.w);

#define GEMM_STORE(ai, idx)                                               \
    if (r0 + idx < n) {                                                   \
        float4 r;                                                         \
        r.x = fmaxf(ai.x + bv.x, 0.f); r.y = fmaxf(ai.y + bv.y, 0.f);     \
        r.z = fmaxf(ai.z + bv.z, 0.f); r.w = fmaxf(ai.w + bv.w, 0.f);     \
        *(float4*)(H + (size_t)(r0 + idx) * 64 + c0) = r;                 \
    }

__global__ __launch_bounds__(256) void k_gemm64(const float* __restrict__ X,
                                                const float* __restrict__ W,
                                                const float* __restrict__ bias,
                                                float* __restrict__ H, int n) {
    __shared__ float Wl[64 * 64];
    {
        const float4* Wv = (const float4*)W;
        float4* Wlv = (float4*)Wl;
        for (int t = threadIdx.x; t < 1024; t += 256) Wlv[t] = Wv[t];
    }
    __syncthreads();
    const int cg = threadIdx.x & 15;     // col group
    const int rg = threadIdx.x >> 4;     // row group
    const int c0 = cg * 4;
    const float4 bv = *(const float4*)(bias + c0);
    const int ntile = (n + 63) >> 6;
    for (int t = blockIdx.x; t < ntile; t += gridDim.x) {
        const int r0 = t * 64 + rg * 4;
        const float* xp0 = X + (size_t)min(r0 + 0, n - 1) * 64;
        const float* xp1 = X + (size_t)min(r0 + 1, n - 1) * 64;
        const float* xp2 = X + (size_t)min(r0 + 2, n - 1) * 64;
        const float* xp3 = X + (size_t)min(r0 + 3, n - 1) * 64;
        float4 a0 = {0,0,0,0}, a1 = {0,0,0,0}, a2 = {0,0,0,0}, a3 = {0,0,0,0};
        #pragma unroll
        for (int k = 0; k < 64; k += 4) {
            const float4 x0 = *(const float4*)(xp0 + k);
            const float4 x1 = *(const float4*)(xp1 + k);
            const float4 x2 = *(const float4*)(xp2 + k);
            const float4 x3 = *(const float4*)(xp3 + k);
            const float4 w0 = *(const float4*)(&Wl[(k + 0) * 64 + c0]);
            const float4 w1 = *(const float4*)(&Wl[(k + 1) * 64 + c0]);
            const float4 w2 = *(const float4*)(&Wl[(k + 2) * 64 + c0]);
            const float4 w3 = *(const float4*)(&Wl[(k + 3) * 64 + c0]);
            GEMM_ACC(a0, x0)
            GEMM_ACC(a1, x1)
            GEMM_ACC(a2, x2)
            GEMM_ACC(a3, x3)
        }
        GEMM_STORE(a0, 0)
        GEMM_STORE(a1, 1)
        GEMM_STORE(a2, 2)
        GEMM_STORE(a3, 3)
    }
}

extern "C" void kernel_launch(void* const* d_in, const int* in_sizes, int n_in,
                              void* d_out, int out_size, void* d_ws, size_t ws_size,
                              hipStream_t stream) {
    const float* emb = (const float*)d_in[0];
    const float* W1  = (const float*)d_in[1];
    const float* b1  = (const float*)d_in[2];
    const float* W2  = (const float*)d_in[3];
    const float* b2  = (const float*)d_in[4];
    const int*   ei  = (const int*)d_in[5];

    const int n  = in_sizes[0] / 64;   // 100000 nodes (< 2^17, fits pack)
    const int ne = in_sizes[5] / 2;    // 1600000 edges
    const int* src = ei;
    const int* dst = ei + ne;
    const int nb = (n + NB_MASK) >> NB_SHIFT;   // 782 buckets

    // ---- workspace layout (~39 MB) ----
    char* ws = (char*)d_ws;
    size_t off = 0;
    auto alloc = [&](size_t bytes) { void* p = ws + off; off = (off + bytes + 63) & ~size_t(63); return p; };
    int*      bcnt    = (int*)     alloc((size_t)nb * 4);
    int*      bbase   = (int*)     alloc((size_t)(nb + 1) * 4);
    int*      bcur    = (int*)     alloc((size_t)nb * 4);
    unsigned* tpack   = (unsigned*)alloc((size_t)ne * 4);
    int*      csrc    = (int*)     alloc((size_t)ne * 4);
    int*      offsets = (int*)     alloc((size_t)(n + 1) * 4);
    float*    dinv    = (float*)   alloc((size_t)n * 4);
    float*    Y       = (float*)   alloc((size_t)n * 64 * 4);
    (void)ws_size;

    float* out = (float*)d_out;   // doubles as X1 between the layers

    hipMemsetAsync(bcnt, 0, (size_t)nb * 4, stream);

    const int pb = (ne + EPB - 1) / EPB;   // partition blocks
    const int wb = (n + 3) / 4;            // 1 wave per node
    const int gb = min((n + 63) / 64, 2048);

    k_bhist<<<pb, 256, 0, stream>>>(dst, bcnt, ne, nb);
    k_bscan<<<1, 64, 0, stream>>>(bcnt, bbase, bcur, nb, offsets, n, ne);
    k_part <<<pb, 256, 0, stream>>>(src, dst, bcur, tpack, ne, nb);
    k_bin  <<<nb, 256, 0, stream>>>(tpack, bbase, csrc, offsets, dinv, n);

    // layer 1
    k_agg   <<<wb, 256, 0, stream>>>(emb, offsets, csrc, dinv, Y, n);
    k_gemm64<<<gb, 256, 0, stream>>>(Y, W1, b1, out, n);
    // layer 2
    k_agg   <<<wb, 256, 0, stream>>>(out, offsets, csrc, dinv, Y, n);
    k_gemm64<<<gb, 256, 0, stream>>>(Y, W2, b2, out, n);
}

// Round 7
// 314.962 us; speedup vs baseline: 2.3654x; 1.0283x over previous
//
#include <hip/hip_runtime.h>
#include <hip/hip_bf16.h>

// ---------------------------------------------------------------------------
// 2-layer GCN on MI355X.
//   relu(agg(X@W)+b) == relu(agg(X)@W + b)   (agg is linear)
// CSR build (bucket partition, no random scatter):
//   k_bhist(vec4) -> k_bscan -> k_part(vec4) -> k_bin1(offsets+dinv)
//   -> k_bin2(cpack = {src, dinv[s]*dinv[d]} 8B, block-exclusive writes)
// Aggregation k_agg: wave/node; edge list LDS-staged (coalesced), inner loop
//   reads (s,w) from LDS broadcast and keeps 8 independent row gathers in
//   flight (no csrc->dinv->gather chain, no random dinv reads).
// GEMM k_gemm64: 4x4 register micro-tile, bias+relu fused.
// Requires n < 2^17 (src packed in 17 bits; n = 100000 here).
// ---------------------------------------------------------------------------

#define NB_SHIFT 7
#define NB_MASK  ((1 << NB_SHIFT) - 1)
#define EPB      8192              // edges per block in bhist/part

__global__ __launch_bounds__(256) void k_bhist(const int* __restrict__ dst,
                                               int* __restrict__ bcnt,
                                               int ne, int nb) {
    __shared__ int lh[1024];
    for (int t = threadIdx.x; t < nb; t += 256) lh[t] = 0;
    __syncthreads();
    const int beg = blockIdx.x * EPB;
    const int end = min(beg + EPB, ne);
    for (int e = beg + threadIdx.x * 4; e < end; e += 1024) {
        if (e + 3 < end) {
            int4 d = *(const int4*)(dst + e);
            atomicAdd(&lh[d.x >> NB_SHIFT], 1);
            atomicAdd(&lh[d.y >> NB_SHIFT], 1);
            atomicAdd(&lh[d.z >> NB_SHIFT], 1);
            atomicAdd(&lh[d.w >> NB_SHIFT], 1);
        } else {
            for (int q = e; q < end; ++q) atomicAdd(&lh[dst[q] >> NB_SHIFT], 1);
        }
    }
    __syncthreads();
    for (int t = threadIdx.x; t < nb; t += 256)
        if (lh[t]) atomicAdd(&bcnt[t], lh[t]);
}

__global__ __launch_bounds__(64) void k_bscan(const int* __restrict__ bcnt,
                                              int* __restrict__ bbase,
                                              int* __restrict__ bcur, int nb,
                                              int* __restrict__ offsets,
                                              int n, int ne) {
    const int lane = threadIdx.x;
    int carry = 0;
    for (int base = 0; base < nb; base += 64) {
        int i = base + lane;
        int v = (i < nb) ? bcnt[i] : 0;
        int x = v;
        #pragma unroll
        for (int off = 1; off < 64; off <<= 1) {
            int t = __shfl_up(x, off);
            if (lane >= off) x += t;
        }
        if (i < nb) { int excl = carry + x - v; bbase[i] = excl; bcur[i] = excl; }
        carry += __shfl(x, 63);
    }
    if (lane == 0) { bbase[nb] = carry; offsets[n] = ne; }
}

__global__ __launch_bounds__(256) void k_part(const int* __restrict__ src,
                                              const int* __restrict__ dst,
                                              int* __restrict__ bcur,
                                              unsigned* __restrict__ tpack,
                                              int ne, int nb) {
    __shared__ int lh[1024];
    __shared__ int lbase[1024];
    __shared__ int lrk[1024];
    for (int t = threadIdx.x; t < nb; t += 256) { lh[t] = 0; lrk[t] = 0; }
    __syncthreads();
    const int beg = blockIdx.x * EPB;
    const int end = min(beg + EPB, ne);
    for (int e = beg + threadIdx.x * 4; e < end; e += 1024) {
        if (e + 3 < end) {
            int4 d = *(const int4*)(dst + e);
            atomicAdd(&lh[d.x >> NB_SHIFT], 1);
            atomicAdd(&lh[d.y >> NB_SHIFT], 1);
            atomicAdd(&lh[d.z >> NB_SHIFT], 1);
            atomicAdd(&lh[d.w >> NB_SHIFT], 1);
        } else {
            for (int q = e; q < end; ++q) atomicAdd(&lh[dst[q] >> NB_SHIFT], 1);
        }
    }
    __syncthreads();
    for (int t = threadIdx.x; t < nb; t += 256)
        lbase[t] = lh[t] ? atomicAdd(&bcur[t], lh[t]) : 0;
    __syncthreads();
    for (int e = beg + threadIdx.x * 4; e < end; e += 1024) {
        if (e + 3 < end) {
            int4 d4 = *(const int4*)(dst + e);
            int4 s4 = *(const int4*)(src + e);
            int b, r;
            b = d4.x >> NB_SHIFT; r = atomicAdd(&lrk[b], 1);
            tpack[lbase[b] + r] = (unsigned)s4.x | ((unsigned)(d4.x & NB_MASK) << 17);
            b = d4.y >> NB_SHIFT; r = atomicAdd(&lrk[b], 1);
            tpack[lbase[b] + r] = (unsigned)s4.y | ((unsigned)(d4.y & NB_MASK) << 17);
            b = d4.z >> NB_SHIFT; r = atomicAdd(&lrk[b], 1);
            tpack[lbase[b] + r] = (unsigned)s4.z | ((unsigned)(d4.z & NB_MASK) << 17);
            b = d4.w >> NB_SHIFT; r = atomicAdd(&lrk[b], 1);
            tpack[lbase[b] + r] = (unsigned)s4.w | ((unsigned)(d4.w & NB_MASK) << 17);
        } else {
            for (int q = e; q < end; ++q) {
                int d = dst[q], s = src[q];
                int b = d >> NB_SHIFT;
                int r = atomicAdd(&lrk[b], 1);
                tpack[lbase[b] + r] = (unsigned)s | ((unsigned)(d & NB_MASK) << 17);
            }
        }
    }
}

// pass 1: per-bucket per-dst hist -> offsets + dinv (no scatter)
__global__ __launch_bounds__(256) void k_bin1(const unsigned* __restrict__ tpack,
                                              const int* __restrict__ bbase,
                                              int* __restrict__ offsets,
                                              float* __restrict__ dinv, int n) {
    __shared__ int hist[128], loff[128];
    const int b = blockIdx.x;
    const int ebeg = bbase[b], eend = bbase[b + 1];
    const int dbase = b << NB_SHIFT;
    if (threadIdx.x < 128) hist[threadIdx.x] = 0;
    __syncthreads();
    for (int e = ebeg + threadIdx.x; e < eend; e += 256)
        atomicAdd(&hist[tpack[e] >> 17], 1);
    __syncthreads();
    if (threadIdx.x < 64) {
        const int lane = threadIdx.x;
        int v0 = hist[lane], v1 = hist[64 + lane];
        int x0 = v0, x1 = v1;
        #pragma unroll
        for (int off = 1; off < 64; off <<= 1) {
            int t0 = __shfl_up(x0, off); if (lane >= off) x0 += t0;
            int t1 = __shfl_up(x1, off); if (lane >= off) x1 += t1;
        }
        int sum0 = __shfl(x0, 63);
        loff[lane]      = x0 - v0;
        loff[64 + lane] = sum0 + x1 - v1;
    }
    __syncthreads();
    if (threadIdx.x < 128) {
        int d = dbase + threadIdx.x;
        if (d < n) {
            offsets[d] = ebeg + loff[threadIdx.x];
            dinv[d]    = rsqrtf((float)(hist[threadIdx.x] + 1));  // +1 self loop
        }
    }
}

// pass 2: scatter cpack = {src, dinv[s]*dinv[d]} into block-exclusive range
__global__ __launch_bounds__(256) void k_bin2(const unsigned* __restrict__ tpack,
                                              const int* __restrict__ bbase,
                                              const float* __restrict__ dinv,
                                              uint2* __restrict__ cpack, int n) {
    __shared__ int hist[128], loff[128], cur[128];
    __shared__ float ldv[128];
    const int b = blockIdx.x;
    const int ebeg = bbase[b], eend = bbase[b + 1];
    const int dbase = b << NB_SHIFT;
    if (threadIdx.x < 128) { hist[threadIdx.x] = 0; cur[threadIdx.x] = 0; }
    __syncthreads();
    for (int e = ebeg + threadIdx.x; e < eend; e += 256)
        atomicAdd(&hist[tpack[e] >> 17], 1);
    __syncthreads();
    if (threadIdx.x < 64) {
        const int lane = threadIdx.x;
        int v0 = hist[lane], v1 = hist[64 + lane];
        int x0 = v0, x1 = v1;
        #pragma unroll
        for (int off = 1; off < 64; off <<= 1) {
            int t0 = __shfl_up(x0, off); if (lane >= off) x0 += t0;
            int t1 = __shfl_up(x1, off); if (lane >= off) x1 += t1;
        }
        int sum0 = __shfl(x0, 63);
        loff[lane]      = x0 - v0;
        loff[64 + lane] = sum0 + x1 - v1;
    }
    __syncthreads();
    if (threadIdx.x < 128) {
        int d = dbase + threadIdx.x;
        ldv[threadIdx.x] = (d < n) ? dinv[d] : 0.f;
    }
    __syncthreads();
    for (int e = ebeg + threadIdx.x; e < eend; e += 256) {
        unsigned p = tpack[e];
        int dl = (int)(p >> 17);
        int s  = (int)(p & 0x1FFFFu);
        int r  = atomicAdd(&cur[dl], 1);
        uint2 q;
        q.x = (unsigned)s;
        q.y = __float_as_uint(dinv[s] * ldv[dl]);
        cpack[ebeg + loff[dl] + r] = q;
    }
}

// Y[i,:] = dinv[i]^2 * X[i,:] + sum_e w[e] * X[s[e],:]
// wave per node. Stage (s,w) pairs into LDS (coalesced read of cpack), then
// inner loop: LDS-broadcast reads + 8 independent float4 row gathers in
// flight per lane. Sentinel pads (s=0,w=0) keep the loop branch-free.
__global__ __launch_bounds__(256) void k_agg(const float* __restrict__ X,
                                             const int* __restrict__ offsets,
                                             const uint2* __restrict__ cpack,
                                             const float* __restrict__ dinv,
                                             float* __restrict__ Y, int n) {
    __shared__ uint2 sw[4][132];
    const int lane = threadIdx.x & 63;
    const int wid  = threadIdx.x >> 6;
    const int sub  = lane >> 4;          // 0..3 edge sub-slot
    const int f0   = (lane & 15) * 4;    // feature offset
    const int i    = (blockIdx.x * 256 + threadIdx.x) >> 6;
    if (i >= n) return;
    const int beg = offsets[i], end = offsets[i + 1];
    const float di = dinv[i];
    float4 acc = {0.f, 0.f, 0.f, 0.f};
    for (int cb = beg; cb < end; cb += 128) {
        const int cnt = min(end - cb, 128);
        const int pad = (cnt + 31) & ~31;
        for (int t = lane; t < pad; t += 64) {
            uint2 p = make_uint2(0u, 0u);          // sentinel: row 0, w = 0
            if (t < cnt) p = cpack[cb + t];
            sw[wid][t] = p;
        }
        // same-wave LDS write->read: lgkmcnt handled by compiler, no barrier
        for (int jb = 0; jb < pad; jb += 32) {
            const int j0 = jb + sub * 8;
            uint2 p[8];
            #pragma unroll
            for (int u = 0; u < 8; ++u) p[u] = sw[wid][j0 + u];
            float4 h[8];
            #pragma unroll
            for (int u = 0; u < 8; ++u)
                h[u] = *(const float4*)(X + (size_t)p[u].x * 64 + f0);
            #pragma unroll
            for (int u = 0; u < 8; ++u) {
                const float w = __uint_as_float(p[u].y);
                acc.x = fmaf(w, h[u].x, acc.x);
                acc.y = fmaf(w, h[u].y, acc.y);
                acc.z = fmaf(w, h[u].z, acc.z);
                acc.w = fmaf(w, h[u].w, acc.w);
            }
        }
    }
    // reduce the 4 sub-slot partials (lanes l, l^16, l^32, l^48)
    acc.x += __shfl_xor(acc.x, 16); acc.x += __shfl_xor(acc.x, 32);
    acc.y += __shfl_xor(acc.y, 16); acc.y += __shfl_xor(acc.y, 32);
    acc.z += __shfl_xor(acc.z, 16); acc.z += __shfl_xor(acc.z, 32);
    acc.w += __shfl_xor(acc.w, 16); acc.w += __shfl_xor(acc.w, 32);
    const float ws = di * di;                       // self loop
    const float4 xs = *(const float4*)(X + (size_t)i * 64 + f0);
    acc.x = fmaf(ws, xs.x, acc.x);
    acc.y = fmaf(ws, xs.y, acc.y);
    acc.z = fmaf(ws, xs.z, acc.z);
    acc.w = fmaf(ws, xs.w, acc.w);
    if (lane < 16) *(float4*)(Y + (size_t)i * 64 + f0) = acc;
}

// H = relu(X @ W + bias); 4x4 micro-tile per thread, 64x64 tile per block.
#define GEMM_ACC(ai, xi)                                                  \
    ai.x = fmaf(xi.x, w0.x, ai.x); ai.y = fmaf(xi.x, w0.y, ai.y);         \
    ai.z = fmaf(xi.x, w0.z, ai.z); ai.w = fmaf(xi.x, w0.w, ai.w);         \
    ai.x = fmaf(xi.y, w1.x, ai.x); ai.y = fmaf(xi.y, w1.y, ai.y);         \
    ai.z = fmaf(xi.y, w1.z, ai.z); ai.w = fmaf(xi.y, w1.w, ai.w);         \
    ai.x = fmaf(xi.z, w2.x, ai.x); ai.y = fmaf(xi.z, w2.y, ai.y);         \
    ai.z = fmaf(xi.z, w2.z, ai.z); ai.w = fmaf(xi.z, w2.w, ai.w);         \
    ai.x = fmaf(xi.w, w3.x, ai.x); ai.y = fmaf(xi.w, w3.y, ai.y);         \
    ai.z = fmaf(xi.w, w3.z, ai.z); ai.w = fmaf(xi.w, w3.w, ai.w);

#define GEMM_STORE(ai, idx)                                               \
    if (r0 + idx < n) {                                                   \
        float4 r;                                                         \
        r.x = fmaxf(ai.x + bv.x, 0.f); r.y = fmaxf(ai.y + bv.y, 0.f);     \
        r.z = fmaxf(ai.z + bv.z, 0.f); r.w = fmaxf(ai.w + bv.w, 0.f);     \
        *(float4*)(H + (size_t)(r0 + idx) * 64 + c0) = r;                 \
    }

__global__ __launch_bounds__(256) void k_gemm64(const float* __restrict__ X,
                                                const float* __restrict__ W,
                                                const float* __restrict__ bias,
                                                float* __restrict__ H, int n) {
    __shared__ float Wl[64 * 64];
    {
        const float4* Wv = (const float4*)W;
        float4* Wlv = (float4*)Wl;
        for (int t = threadIdx.x; t < 1024; t += 256) Wlv[t] = Wv[t];
    }
    __syncthreads();
    const int cg = threadIdx.x & 15;     // col group
    const int rg = threadIdx.x >> 4;     // row group
    const int c0 = cg * 4;
    const float4 bv = *(const float4*)(bias + c0);
    const int ntile = (n + 63) >> 6;
    for (int t = blockIdx.x; t < ntile; t += gridDim.x) {
        const int r0 = t * 64 + rg * 4;
        const float* xp0 = X + (size_t)min(r0 + 0, n - 1) * 64;
        const float* xp1 = X + (size_t)min(r0 + 1, n - 1) * 64;
        const float* xp2 = X + (size_t)min(r0 + 2, n - 1) * 64;
        const float* xp3 = X + (size_t)min(r0 + 3, n - 1) * 64;
        float4 a0 = {0,0,0,0}, a1 = {0,0,0,0}, a2 = {0,0,0,0}, a3 = {0,0,0,0};
        #pragma unroll
        for (int k = 0; k < 64; k += 4) {
            const float4 x0 = *(const float4*)(xp0 + k);
            const float4 x1 = *(const float4*)(xp1 + k);
            const float4 x2 = *(const float4*)(xp2 + k);
            const float4 x3 = *(const float4*)(xp3 + k);
            const float4 w0 = *(const float4*)(&Wl[(k + 0) * 64 + c0]);
            const float4 w1 = *(const float4*)(&Wl[(k + 1) * 64 + c0]);
            const float4 w2 = *(const float4*)(&Wl[(k + 2) * 64 + c0]);
            const float4 w3 = *(const float4*)(&Wl[(k + 3) * 64 + c0]);
            GEMM_ACC(a0, x0)
            GEMM_ACC(a1, x1)
            GEMM_ACC(a2, x2)
            GEMM_ACC(a3, x3)
        }
        GEMM_STORE(a0, 0)
        GEMM_STORE(a1, 1)
        GEMM_STORE(a2, 2)
        GEMM_STORE(a3, 3)
    }
}

extern "C" void kernel_launch(void* const* d_in, const int* in_sizes, int n_in,
                              void* d_out, int out_size, void* d_ws, size_t ws_size,
                              hipStream_t stream) {
    const float* emb = (const float*)d_in[0];
    const float* W1  = (const float*)d_in[1];
    const float* b1  = (const float*)d_in[2];
    const float* W2  = (const float*)d_in[3];
    const float* b2  = (const float*)d_in[4];
    const int*   ei  = (const int*)d_in[5];

    const int n  = in_sizes[0] / 64;   // 100000 nodes (< 2^17, fits pack)
    const int ne = in_sizes[5] / 2;    // 1600000 edges
    const int* src = ei;
    const int* dst = ei + ne;
    const int nb = (n + NB_MASK) >> NB_SHIFT;   // 782 buckets

    // ---- workspace layout (~39 MB; tpack aliased with Y) ----
    char* ws = (char*)d_ws;
    size_t off = 0;
    auto alloc = [&](size_t bytes) { void* p = ws + off; off = (off + bytes + 63) & ~size_t(63); return p; };
    int*      bcnt    = (int*)  alloc((size_t)nb * 4);
    int*      bbase   = (int*)  alloc((size_t)(nb + 1) * 4);
    int*      bcur    = (int*)  alloc((size_t)nb * 4);
    int*      offsets = (int*)  alloc((size_t)(n + 1) * 4);
    float*    dinv    = (float*)alloc((size_t)n * 4);
    uint2*    cpack   = (uint2*)alloc((size_t)ne * 8);
    size_t ybytes = (size_t)n * 64 * 4;
    size_t tbytes = (size_t)ne * 4;
    void* yt = alloc(ybytes > tbytes ? ybytes : tbytes);
    unsigned* tpack = (unsigned*)yt;   // dead after k_bin2
    float*    Y     = (float*)yt;      // live from first k_agg on
    (void)ws_size;

    float* out = (float*)d_out;   // doubles as X1 between the layers

    hipMemsetAsync(bcnt, 0, (size_t)nb * 4, stream);

    const int pb = (ne + EPB - 1) / EPB;   // partition blocks
    const int wb = (n + 3) / 4;            // 1 wave per node
    const int gb = min((n + 63) / 64, 2048);

    k_bhist<<<pb, 256, 0, stream>>>(dst, bcnt, ne, nb);
    k_bscan<<<1, 64, 0, stream>>>(bcnt, bbase, bcur, nb, offsets, n, ne);
    k_part <<<pb, 256, 0, stream>>>(src, dst, bcur, tpack, ne, nb);
    k_bin1 <<<nb, 256, 0, stream>>>(tpack, bbase, offsets, dinv, n);
    k_bin2 <<<nb, 256, 0, stream>>>(tpack, bbase, dinv, cpack, n);

    // layer 1
    k_agg   <<<wb, 256, 0, stream>>>(emb, offsets, cpack, dinv, Y, n);
    k_gemm64<<<gb, 256, 0, stream>>>(Y, W1, b1, out, n);
    // layer 2
    k_agg   <<<wb, 256, 0, stream>>>(out, offsets, cpack, dinv, Y, n);
    k_gemm64<<<gb, 256, 0, stream>>>(Y, W2, b2, out, n);
}